// Round 1
// baseline (702.635 us; speedup 1.0000x reference)
//
#include <hip/hip_runtime.h>
#include <math.h>

// Problem constants (fixed by setup_inputs)
#define DM   256
#define LQ   11253
#define NTOK (2*LQ)
#define NH   8
#define NL   4
#define NP   4
#define TA   8   // tokens per block, kernel A
#define TB   8   // tokens per block, kernel B

// ---------------- helpers ----------------

// acc[t] = bias[j] + sum_k rows[t][k] * W[k*DOUT + j]
template<int T, int DOUT>
__device__ __forceinline__ void matvec_rows(const float (*rows)[DM],
                                            const float* __restrict__ W,
                                            const float* __restrict__ bias,
                                            int j, float (&acc)[T]) {
#pragma unroll
  for (int t = 0; t < T; ++t) acc[t] = bias[j];
#pragma unroll 4
  for (int k4 = 0; k4 < DM / 4; ++k4) {
    const float w0 = W[(4 * k4 + 0) * DOUT + j];
    const float w1 = W[(4 * k4 + 1) * DOUT + j];
    const float w2 = W[(4 * k4 + 2) * DOUT + j];
    const float w3 = W[(4 * k4 + 3) * DOUT + j];
#pragma unroll
    for (int t = 0; t < T; ++t) {
      const float4 r = *reinterpret_cast<const float4*>(&rows[t][4 * k4]);
      acc[t] = fmaf(r.x, w0, acc[t]);
      acc[t] = fmaf(r.y, w1, acc[t]);
      acc[t] = fmaf(r.z, w2, acc[t]);
      acc[t] = fmaf(r.w, w3, acc[t]);
    }
  }
}

// per-row (token) block-wide sum; 256 threads = 4 waves
template<int T>
__device__ __forceinline__ void block_row_sums(const float (&x)[T], float (&s)[T],
                                               float (*part)[4], int tid) {
  const int lane = tid & 63, wave = tid >> 6;
#pragma unroll
  for (int t = 0; t < T; ++t) {
    float v = x[t];
#pragma unroll
    for (int o = 32; o; o >>= 1) v += __shfl_down(v, o);
    if (lane == 0) part[t][wave] = v;
  }
  __syncthreads();
#pragma unroll
  for (int t = 0; t < T; ++t) s[t] = part[t][0] + part[t][1] + part[t][2] + part[t][3];
  __syncthreads();  // make part reusable
}

template<int T>
__device__ __forceinline__ void block_ln(float (&x)[T], float (*part)[4], int tid,
                                         const float* __restrict__ g,
                                         const float* __restrict__ be) {
  float s[T];
  block_row_sums<T>(x, s, part, tid);
  float m[T];
#pragma unroll
  for (int t = 0; t < T; ++t) m[t] = s[t] * (1.0f / DM);
  float d2[T];
#pragma unroll
  for (int t = 0; t < T; ++t) { const float dd = x[t] - m[t]; d2[t] = dd * dd; }
  block_row_sums<T>(d2, s, part, tid);
  const float gj = g[tid], bj = be[tid];
#pragma unroll
  for (int t = 0; t < T; ++t) {
    const float var = s[t] * (1.0f / DM);
    x[t] = (x[t] - m[t]) * rsqrtf(var + 1e-5f) * gj + bj;
  }
}

// ---------------- kernel A: value = LN(src @ w_ds) @ w_val ----------------

__global__ __launch_bounds__(256) void k_value(
    const float* __restrict__ src,
    const float* __restrict__ w_ds, const float* __restrict__ b_ds,
    const float* __restrict__ g_ds, const float* __restrict__ be_ds,
    const float* __restrict__ w_val, const float* __restrict__ b_val,
    float* __restrict__ value) {
  __shared__ __align__(16) float rows[TA][DM];
  __shared__ float part[TA][4];
  const int j = threadIdx.x;
  const int tok0 = blockIdx.x * TA;

#pragma unroll
  for (int t = 0; t < TA; ++t) {
    const int tok = tok0 + t;
    rows[t][j] = (tok < NTOK) ? src[(size_t)tok * DM + j] : 0.f;
  }
  __syncthreads();

  float acc[TA];
  matvec_rows<TA, DM>(rows, w_ds, b_ds, j, acc);
  block_ln<TA>(acc, part, j, g_ds, be_ds);   // internal syncs cover rows reuse
#pragma unroll
  for (int t = 0; t < TA; ++t) rows[t][j] = acc[t];
  __syncthreads();
  matvec_rows<TA, DM>(rows, w_val, b_val, j, acc);
#pragma unroll
  for (int t = 0; t < TA; ++t) {
    const int tok = tok0 + t;
    if (tok < NTOK) value[(size_t)tok * DM + j] = acc[t];
  }
}

// ---------------- kernel B: deform-attn + FFN tail ----------------

__global__ __launch_bounds__(256) void k_attn(
    const float* __restrict__ tgt, const float* __restrict__ qp, const float* __restrict__ ref,
    const float* __restrict__ w_off, const float* __restrict__ b_off,
    const float* __restrict__ w_attn, const float* __restrict__ b_attn,
    const float* __restrict__ value,
    const float* __restrict__ w_out, const float* __restrict__ b_out,
    const float* __restrict__ w_cs, const float* __restrict__ b_cs,
    const float* __restrict__ g1, const float* __restrict__ be1,
    const float* __restrict__ w1, const float* __restrict__ b1,
    const float* __restrict__ g2, const float* __restrict__ be2,
    float* __restrict__ out) {
  __shared__ __align__(16) float qrow[TB][DM];   // q, later t2a rows
  __shared__ __align__(16) float tg[TB][DM];     // tgt residual
  __shared__ __align__(16) float offs[TB][DM];   // offsets, later t rows
  __shared__ __align__(16) float aw[TB][NH * 16];
  __shared__ __align__(16) float attn[TB][DM];
  __shared__ float part[TB][4];
  const int j = threadIdx.x;
  const int tok0 = blockIdx.x * TB;

  // 1. load q = tgt + query_pos (keep tgt for residual)
#pragma unroll
  for (int t = 0; t < TB; ++t) {
    const int tok = tok0 + t;
    const float tv = (tok < NTOK) ? tgt[(size_t)tok * DM + j] : 0.f;
    const float pv = (tok < NTOK) ? qp[(size_t)tok * DM + j] : 0.f;
    tg[t][j] = tv;
    qrow[t][j] = tv + pv;
  }
  __syncthreads();

  float acc[TB];
  // 2. sampling offsets: q @ w_off + b_off
  matvec_rows<TB, DM>(qrow, w_off, b_off, j, acc);
#pragma unroll
  for (int t = 0; t < TB; ++t) offs[t][j] = acc[t];
  // 3. attention logits: q @ w_attn + b_attn (128 outputs)
  if (j < 128) {
    float a2[TB];
    matvec_rows<TB, 128>(qrow, w_attn, b_attn, j, a2);
#pragma unroll
    for (int t = 0; t < TB; ++t) aw[t][j] = a2[t];
  }
  __syncthreads();
  // 4. softmax over 16 per (token, head)
  if (j < TB * NH) {
    const int t = j >> 3, h = j & 7;
    float* a = &aw[t][h * 16];
    float m = a[0];
#pragma unroll
    for (int i = 1; i < 16; ++i) m = fmaxf(m, a[i]);
    float s = 0.f, e[16];
#pragma unroll
    for (int i = 0; i < 16; ++i) { e[i] = expf(a[i] - m); s += e[i]; }
    const float inv = 1.0f / s;
#pragma unroll
    for (int i = 0; i < 16; ++i) a[i] = e[i] * inv;
  }
  __syncthreads();

  // 5. bilinear sampling. thread j -> head h = j>>5, dim d = j&31 (j = h*32+d)
  const int h = j >> 5;
  constexpr int LSI_[4] = {0, 8464, 10580, 11109};
  constexpr int WD_[4] = {92, 46, 23, 12};
#pragma unroll 1
  for (int t = 0; t < TB; ++t) {
    const int tok = tok0 + t;
    float oacc = 0.f;
    if (tok < NTOK) {
      const int bb = (tok >= LQ) ? 1 : 0;
      const int vbase = bb * LQ;
#pragma unroll 1
      for (int l = 0; l < NL; ++l) {
        const float refx = ref[(size_t)tok * 8 + l * 2 + 0];
        const float refy = ref[(size_t)tok * 8 + l * 2 + 1];
        const int Wl = WD_[l];
        const float fW = (float)Wl, invW = 1.0f / fW;
        const int rbase = vbase + LSI_[l];
#pragma unroll
        for (int p = 0; p < NP; ++p) {
          const float ox = offs[t][((h * NL + l) * NP + p) * 2 + 0];
          const float oy = offs[t][((h * NL + l) * NP + p) * 2 + 1];
          const float a = aw[t][h * 16 + l * 4 + p];
          const float x = (refx + ox * invW) * fW - 0.5f;
          const float y = (refy + oy * invW) * fW - 0.5f;
          const float x0f = floorf(x), y0f = floorf(y);
          const int x0 = (int)x0f, y0 = (int)y0f;
          const float fx = x - x0f, fy = y - y0f;
          const float s00 = (1.f - fx) * (1.f - fy), s10 = fx * (1.f - fy);
          const float s01 = (1.f - fx) * fy,        s11 = fx * fy;
          const bool xv0 = (x0 >= 0) && (x0 < Wl), xv1 = (x0 + 1 >= 0) && (x0 + 1 < Wl);
          const bool yv0 = (y0 >= 0) && (y0 < Wl), yv1 = (y0 + 1 >= 0) && (y0 + 1 < Wl);
          float v00 = 0.f, v10 = 0.f, v01 = 0.f, v11 = 0.f;
          if (yv0) {
            const int rb = (rbase + y0 * Wl) * DM + j;
            if (xv0) v00 = value[rb + x0 * DM];
            if (xv1) v10 = value[rb + (x0 + 1) * DM];
          }
          if (yv1) {
            const int rb = (rbase + (y0 + 1) * Wl) * DM + j;
            if (xv0) v01 = value[rb + x0 * DM];
            if (xv1) v11 = value[rb + (x0 + 1) * DM];
          }
          oacc += a * (s00 * v00 + s10 * v10 + s01 * v01 + s11 * v11);
        }
      }
    }
    attn[t][j] = oacc;
  }
  __syncthreads();

  // 6. t2a = attn @ w_out + b_out  (reuse qrow)
  matvec_rows<TB, DM>(attn, w_out, b_out, j, acc);
#pragma unroll
  for (int t = 0; t < TB; ++t) qrow[t][j] = acc[t];
  __syncthreads();

  // 7. t2 = t2a @ w_cs + b_cs; x = tgt + t2; LN1 -> t (store in offs)
  matvec_rows<TB, DM>(qrow, w_cs, b_cs, j, acc);
#pragma unroll
  for (int t = 0; t < TB; ++t) acc[t] += tg[t][j];
  block_ln<TB>(acc, part, j, g1, be1);
  float tv[TB];
#pragma unroll
  for (int t = 0; t < TB; ++t) { tv[t] = acc[t]; offs[t][j] = acc[t]; }
  __syncthreads();

  // 8. u = gelu(t @ w1 + b1); y = t + u
  matvec_rows<TB, DM>(offs, w1, b1, j, acc);
#pragma unroll
  for (int t = 0; t < TB; ++t) {
    const float x = acc[t];
    acc[t] = tv[t] + 0.5f * x * (1.0f + erff(x * 0.70710678118654752f));
  }

  // 9. LN2 -> out
  block_ln<TB>(acc, part, j, g2, be2);
#pragma unroll
  for (int t = 0; t < TB; ++t) {
    const int tok = tok0 + t;
    if (tok < NTOK) out[(size_t)tok * DM + j] = acc[t];
  }
}

// ---------------- launch ----------------

extern "C" void kernel_launch(void* const* d_in, const int* in_sizes, int n_in,
                              void* d_out, int out_size, void* d_ws, size_t ws_size,
                              hipStream_t stream) {
  const float* tgt    = (const float*)d_in[0];
  const float* qp     = (const float*)d_in[1];
  const float* ref    = (const float*)d_in[2];
  const float* src    = (const float*)d_in[3];
  // d_in[4] spatial shapes, d_in[5] level_start_index: int32, hardcoded
  const float* w_ds   = (const float*)d_in[6];
  const float* b_ds   = (const float*)d_in[7];
  const float* g_ds   = (const float*)d_in[8];
  const float* be_ds  = (const float*)d_in[9];
  const float* w_off  = (const float*)d_in[10];
  const float* b_off  = (const float*)d_in[11];
  const float* w_attn = (const float*)d_in[12];
  const float* b_attn = (const float*)d_in[13];
  const float* w_val  = (const float*)d_in[14];
  const float* b_val  = (const float*)d_in[15];
  const float* w_out  = (const float*)d_in[16];
  const float* b_out  = (const float*)d_in[17];
  const float* w_cs   = (const float*)d_in[18];
  const float* b_cs   = (const float*)d_in[19];
  const float* g1     = (const float*)d_in[20];
  const float* be1    = (const float*)d_in[21];
  const float* w1     = (const float*)d_in[22];
  const float* b1     = (const float*)d_in[23];
  const float* g2     = (const float*)d_in[24];
  const float* be2    = (const float*)d_in[25];

  float* value = (float*)d_ws;  // NTOK * 256 * 4 = 23.0 MB
  float* out   = (float*)d_out;

  const int blocksA = (NTOK + TA - 1) / TA;
  const int blocksB = (NTOK + TB - 1) / TB;
  hipLaunchKernelGGL(k_value, dim3(blocksA), dim3(256), 0, stream,
                     src, w_ds, b_ds, g_ds, be_ds, w_val, b_val, value);
  hipLaunchKernelGGL(k_attn, dim3(blocksB), dim3(256), 0, stream,
                     tgt, qp, ref, w_off, b_off, w_attn, b_attn, value,
                     w_out, b_out, w_cs, b_cs, g1, be1, w1, b1, g2, be2, out);
}

// Round 2
// 202.289 us; speedup vs baseline: 3.4734x; 3.4734x over previous
//
#include <hip/hip_runtime.h>
#include <math.h>

// Problem constants (fixed by setup_inputs)
#define DM   256
#define LQ   11253
#define NTOK (2*LQ)
#define TT   16      // tokens per block
#define AS   264     // ushorts per A (bf16) LDS row: 256 + 8 pad
#define CS   260     // floats per C (fp32) LDS row: 256 + 4 pad
#define AWS  132     // floats per AW row: 128 + 4 pad

typedef __attribute__((ext_vector_type(8))) short bf16x8;  // 8 bf16 in 4 VGPRs
typedef __attribute__((ext_vector_type(4))) float f32x4;

// packed-weight offsets (ushort units); each N=256 weight = 8kt*16nt*64lane*8 = 65536
#define PW_DS  0
#define PW_VAL 65536
#define PW_OFF 131072
#define PW_OUT 196608
#define PW_CS  262144
#define PW_W1  327680
#define PW_ATT 393216   // w_attn, N=128 -> 32768 elems
#define PW_TOTAL 425984 // ushorts = 851,968 bytes
#define VALUE_WS_OFF (1u<<20)  // value bf16 buffer at +1 MiB in d_ws

// ---------------- small helpers ----------------

__device__ __forceinline__ ushort f2b(float x) {   // fp32 -> bf16 (RNE)
  union { float f; unsigned u; } c; c.f = x;
  unsigned u = c.u + 0x7fffu + ((c.u >> 16) & 1u);
  return (ushort)(u >> 16);
}
__device__ __forceinline__ float blo(unsigned u) { // low bf16 of a pair -> fp32
  union { unsigned u; float f; } c; c.u = u << 16; return c.f;
}
__device__ __forceinline__ float bhi(unsigned u) { // high bf16 of a pair -> fp32
  union { unsigned u; float f; } c; c.u = u & 0xffff0000u; return c.f;
}

// ---------------- weight pack: fp32 [K][N] -> bf16 MFMA B-fragments ----------
// fragment f = nt*8 + kt (kt = K/32 index, nt = N/16 index)
// out[(f*64 + l)*8 + e] = bf16( W[(kt*32 + (l>>4)*8 + e)*N + nt*16 + (l&15)] )

__global__ __launch_bounds__(256) void k_pack(
    const float* __restrict__ w0, const float* __restrict__ w1,
    const float* __restrict__ w2, const float* __restrict__ w3,
    const float* __restrict__ w4, const float* __restrict__ w5,
    const float* __restrict__ wa, ushort* __restrict__ out) {
  const int gid = blockIdx.x * 256 + threadIdx.x;
  const float* W; int N; size_t obase; int local;
  if (gid < 6 * 8192) {
    const int wi = gid >> 13; local = gid & 8191; N = 256;
    obase = (size_t)wi * 65536;
    W = (wi == 0) ? w0 : (wi == 1) ? w1 : (wi == 2) ? w2
      : (wi == 3) ? w3 : (wi == 4) ? w4 : w5;
  } else {
    local = gid - 6 * 8192; N = 128; obase = PW_ATT; W = wa;
  }
  const int l = local & 63, f = local >> 6;
  const int kt = f & 7, nt = f >> 3;
  const int k0 = kt * 32 + (l >> 4) * 8, col = nt * 16 + (l & 15);
  ushort v[8];
#pragma unroll
  for (int e = 0; e < 8; ++e) v[e] = f2b(W[(size_t)(k0 + e) * N + col]);
  *reinterpret_cast<uint4*>(&out[obase + (size_t)local * 8]) =
      *reinterpret_cast<const uint4*>(v);
}

// ---------------- GEMM tile: C[16 x 16*NTW] += A[16x256] * B ----------------
// A: LDS bf16 [16][AS]; Bp: packed global; wave handles nt = ntBase..ntBase+NTW-1

template<int NTW>
__device__ __forceinline__ void gemm_tile(const ushort* __restrict__ A,
                                          const ushort* __restrict__ Bp,
                                          int ntBase, int lane,
                                          f32x4 (&acc)[NTW]) {
  const int r = lane & 15, hk = lane >> 4;
  const ushort* arow = A + r * AS + hk * 8;
#pragma unroll
  for (int nt = 0; nt < NTW; ++nt) acc[nt] = (f32x4){0.f, 0.f, 0.f, 0.f};
#pragma unroll
  for (int kt = 0; kt < 8; ++kt) {
    const bf16x8 a = *(const bf16x8*)(arow + kt * 32);
#pragma unroll
    for (int nt = 0; nt < NTW; ++nt) {
      const bf16x8 b = *(const bf16x8*)(Bp + ((size_t)((ntBase + nt) * 8 + kt) * 64 + lane) * 8);
      acc[nt] = __builtin_amdgcn_mfma_f32_16x16x32_bf16(a, b, acc[nt], 0, 0, 0);
    }
  }
}

// epilogue: acc + bias -> C fp32 LDS (C/D layout: col=lane&15, row=(lane>>4)*4+i)
template<int NTW>
__device__ __forceinline__ void acc_to_c(const f32x4 (&acc)[NTW], float* C,
                                         const float* __restrict__ bias,
                                         int ntBase, int lane, int rowStride) {
  const int col = lane & 15, rb = (lane >> 4) * 4;
#pragma unroll
  for (int nt = 0; nt < NTW; ++nt) {
    const int dim = (ntBase + nt) * 16 + col;
    const float bj = bias[dim];
#pragma unroll
    for (int i = 0; i < 4; ++i) C[(rb + i) * rowStride + dim] = acc[nt][i] + bj;
  }
}

// load fp32 rows (optionally X+Y) -> bf16 A tile; wave w handles tokens 4w..4w+3
template<bool ADD>
__device__ __forceinline__ void load_to_A(const float* __restrict__ X,
                                          const float* __restrict__ Y,
                                          int tok0, ushort* A, int w, int lane) {
#pragma unroll
  for (int tt = 0; tt < 4; ++tt) {
    const int t = w * 4 + tt, tok = tok0 + t;
    float4 v = make_float4(0.f, 0.f, 0.f, 0.f);
    if (tok < NTOK) {
      v = *reinterpret_cast<const float4*>(&X[(size_t)tok * DM + lane * 4]);
      if (ADD) {
        const float4 y = *reinterpret_cast<const float4*>(&Y[(size_t)tok * DM + lane * 4]);
        v.x += y.x; v.y += y.y; v.z += y.z; v.w += y.w;
      }
    }
    ushort4 b; b.x = f2b(v.x); b.y = f2b(v.y); b.z = f2b(v.z); b.w = f2b(v.w);
    *reinterpret_cast<ushort4*>(&A[t * AS + lane * 4]) = b;
  }
}

// LayerNorm rows of C -> bf16 into A (and optionally fp32 back into C)
template<bool WRITEBACK>
__device__ __forceinline__ void ln_c_to_a(float* C, ushort* A,
                                          const float* __restrict__ g,
                                          const float* __restrict__ be,
                                          int w, int lane) {
#pragma unroll
  for (int tt = 0; tt < 4; ++tt) {
    const int t = w * 4 + tt;
    float4 v = *reinterpret_cast<float4*>(&C[t * CS + lane * 4]);
    float s = v.x + v.y + v.z + v.w;
#pragma unroll
    for (int o = 32; o; o >>= 1) s += __shfl_xor(s, o);
    const float m = s * (1.f / 256.f);
    const float d0 = v.x - m, d1 = v.y - m, d2 = v.z - m, d3 = v.w - m;
    float s2 = d0 * d0 + d1 * d1 + d2 * d2 + d3 * d3;
#pragma unroll
    for (int o = 32; o; o >>= 1) s2 += __shfl_xor(s2, o);
    const float rs = rsqrtf(s2 * (1.f / 256.f) + 1e-5f);
    const float4 gg = *reinterpret_cast<const float4*>(&g[lane * 4]);
    const float4 bb = *reinterpret_cast<const float4*>(&be[lane * 4]);
    float4 o4;
    o4.x = d0 * rs * gg.x + bb.x; o4.y = d1 * rs * gg.y + bb.y;
    o4.z = d2 * rs * gg.z + bb.z; o4.w = d3 * rs * gg.w + bb.w;
    ushort4 ob; ob.x = f2b(o4.x); ob.y = f2b(o4.y); ob.z = f2b(o4.z); ob.w = f2b(o4.w);
    *reinterpret_cast<ushort4*>(&A[t * AS + lane * 4]) = ob;
    if (WRITEBACK) *reinterpret_cast<float4*>(&C[t * CS + lane * 4]) = o4;
  }
}

// plain convert C fp32 -> A bf16
__device__ __forceinline__ void c_to_a(const float* C, ushort* A, int w, int lane) {
#pragma unroll
  for (int tt = 0; tt < 4; ++tt) {
    const int t = w * 4 + tt;
    const float4 v = *reinterpret_cast<const float4*>(&C[t * CS + lane * 4]);
    ushort4 ob; ob.x = f2b(v.x); ob.y = f2b(v.y); ob.z = f2b(v.z); ob.w = f2b(v.w);
    *reinterpret_cast<ushort4*>(&A[t * AS + lane * 4]) = ob;
  }
}

// ---------------- kernel A: value = LN(src @ w_ds) @ w_val  (bf16 out) -------

__global__ __launch_bounds__(256) void k_value(
    const float* __restrict__ src, const ushort* __restrict__ pw,
    const float* __restrict__ b_ds, const float* __restrict__ g_ds,
    const float* __restrict__ be_ds, const float* __restrict__ b_val,
    ushort* __restrict__ value) {
  __shared__ __align__(16) ushort A[TT * AS];
  __shared__ __align__(16) float  C[TT * CS];
  const int tid = threadIdx.x, w = tid >> 6, lane = tid & 63;
  const int tok0 = blockIdx.x * TT;

  load_to_A<false>(src, nullptr, tok0, A, w, lane);
  __syncthreads();
  f32x4 acc[4];
  gemm_tile<4>(A, pw + PW_DS, w * 4, lane, acc);
  acc_to_c<4>(acc, C, b_ds, w * 4, lane, CS);
  __syncthreads();
  ln_c_to_a<false>(C, A, g_ds, be_ds, w, lane);
  __syncthreads();
  gemm_tile<4>(A, pw + PW_VAL, w * 4, lane, acc);
  acc_to_c<4>(acc, C, b_val, w * 4, lane, CS);
  __syncthreads();
  // store bf16 value rows (wave per 4 tokens, 8B/lane coalesced)
#pragma unroll
  for (int tt = 0; tt < 4; ++tt) {
    const int t = w * 4 + tt, tok = tok0 + t;
    if (tok < NTOK) {
      const float4 v = *reinterpret_cast<const float4*>(&C[t * CS + lane * 4]);
      ushort4 b; b.x = f2b(v.x); b.y = f2b(v.y); b.z = f2b(v.z); b.w = f2b(v.w);
      *reinterpret_cast<ushort4*>(&value[(size_t)tok * DM + lane * 4]) = b;
    }
  }
}

// ---------------- kernel B: deform-attn + FFN tail ----------------

__global__ __launch_bounds__(256) void k_attn(
    const float* __restrict__ tgt, const float* __restrict__ qp,
    const float* __restrict__ ref, const ushort* __restrict__ pw,
    const float* __restrict__ b_off, const float* __restrict__ b_attn,
    const ushort* __restrict__ value,
    const float* __restrict__ b_out, const float* __restrict__ b_cs,
    const float* __restrict__ g1, const float* __restrict__ be1,
    const float* __restrict__ b1,
    const float* __restrict__ g2, const float* __restrict__ be2,
    float* __restrict__ out) {
  __shared__ __align__(16) ushort A[TT * AS];
  __shared__ __align__(16) float  C[TT * CS];
  __shared__ __align__(16) float  AW[TT * AWS];
  const int tid = threadIdx.x, w = tid >> 6, lane = tid & 63;
  const int tok0 = blockIdx.x * TT;

  // 1. q = tgt + query_pos -> A bf16
  load_to_A<true>(tgt, qp, tok0, A, w, lane);
  __syncthreads();

  f32x4 acc[4];
  // 2. sampling offsets: q @ w_off + b_off -> C fp32
  gemm_tile<4>(A, pw + PW_OFF, w * 4, lane, acc);
  acc_to_c<4>(acc, C, b_off, w * 4, lane, CS);
  // 3. attention logits: q @ w_attn + b_attn -> AW fp32 (N=128, 2 nt/wave)
  {
    f32x4 a2[2];
    gemm_tile<2>(A, pw + PW_ATT, w * 2, lane, a2);
    acc_to_c<2>(a2, AW, b_attn, w * 2, lane, AWS);
  }
  __syncthreads();

  // 4. softmax over 16 per (token, head)
  if (tid < TT * 8) {
    const int t = tid >> 3, h = tid & 7;
    float* a = &AW[t * AWS + h * 16];
    float m = a[0];
#pragma unroll
    for (int i = 1; i < 16; ++i) m = fmaxf(m, a[i]);
    float s = 0.f, e[16];
#pragma unroll
    for (int i = 0; i < 16; ++i) { e[i] = expf(a[i] - m); s += e[i]; }
    const float inv = 1.0f / s;
#pragma unroll
    for (int i = 0; i < 16; ++i) a[i] = e[i] * inv;
  }
  __syncthreads();

  // 5. bilinear gather from bf16 value. 16 lanes/head, 2 dims/thread.
  //    tid -> head hh=(tid>>4)&7, pair d2=tid&15, token half = (tid>>7)*8
  {
    const int hh = (tid >> 4) & 7;
    const int d2 = tid & 15;
    const int cix = hh * 16 + d2;          // uint column within a value row
    const int cdim = hh * 32 + d2 * 2;     // bf16 dim
    const int thalf = (tid >> 7) * 8;
    const unsigned* __restrict__ vbuf = (const unsigned*)value;
    constexpr int LSI_[4] = {0, 8464, 10580, 11109};
    constexpr int WD_[4] = {92, 46, 23, 12};
#pragma unroll 1
    for (int ti = 0; ti < 8; ++ti) {
      const int t = thalf + ti, tok = tok0 + t;
      float o0 = 0.f, o1 = 0.f;
      if (tok < NTOK) {
        const int vbase = (tok >= LQ) ? LQ : 0;
#pragma unroll 1
        for (int l = 0; l < 4; ++l) {
          const float refx = ref[(size_t)tok * 8 + l * 2 + 0];
          const float refy = ref[(size_t)tok * 8 + l * 2 + 1];
          const int Wl = WD_[l];
          const float fW = (float)Wl;
          const int rbas = vbase + LSI_[l];
#pragma unroll
          for (int p = 0; p < 4; ++p) {
            const float ox = C[t * CS + ((hh * 4 + l) * 4 + p) * 2 + 0];
            const float oy = C[t * CS + ((hh * 4 + l) * 4 + p) * 2 + 1];
            const float aw = AW[t * AWS + hh * 16 + l * 4 + p];
            const float x = fmaf(refx, fW, ox) - 0.5f;
            const float y = fmaf(refy, fW, oy) - 0.5f;
            const float x0f = floorf(x), y0f = floorf(y);
            const int x0 = (int)x0f, y0 = (int)y0f;
            const float fx = x - x0f, fy = y - y0f;
            const float gx = 1.f - fx, gy = 1.f - fy;
            const float s00 = gx * gy, s10 = fx * gy, s01 = gx * fy, s11 = fx * fy;
            const bool xv0 = (x0 >= 0) & (x0 < Wl);
            const bool xv1 = (x0 >= -1) & (x0 < Wl - 1);
            const bool yv0 = (y0 >= 0) & (y0 < Wl);
            const bool yv1 = (y0 >= -1) & (y0 < Wl - 1);
            unsigned u00 = 0, u10 = 0, u01 = 0, u11 = 0;
            if (yv0) {
              const int rb = (rbas + y0 * Wl) * 128 + cix;
              if (xv0) u00 = vbuf[rb + x0 * 128];
              if (xv1) u10 = vbuf[rb + x0 * 128 + 128];
            }
            if (yv1) {
              const int rb = (rbas + (y0 + 1) * Wl) * 128 + cix;
              if (xv0) u01 = vbuf[rb + x0 * 128];
              if (xv1) u11 = vbuf[rb + x0 * 128 + 128];
            }
            const float lo = s00 * blo(u00) + s10 * blo(u10) + s01 * blo(u01) + s11 * blo(u11);
            const float hi = s00 * bhi(u00) + s10 * bhi(u10) + s01 * bhi(u01) + s11 * bhi(u11);
            o0 = fmaf(aw, lo, o0);
            o1 = fmaf(aw, hi, o1);
          }
        }
      }
      // write attn result directly into A as bf16 pair (A/q is dead by now)
      const unsigned u = (unsigned)f2b(o0) | ((unsigned)f2b(o1) << 16);
      *reinterpret_cast<unsigned*>(&A[(size_t)t * AS + cdim]) = u;
    }
  }
  __syncthreads();

  // 6. t2a = attn @ w_out + b_out -> C
  gemm_tile<4>(A, pw + PW_OUT, w * 4, lane, acc);
  acc_to_c<4>(acc, C, b_out, w * 4, lane, CS);
  __syncthreads();
  c_to_a(C, A, w, lane);
  __syncthreads();

  // 7. t2 = t2a @ w_cs + b_cs + tgt -> C; LN1 -> A bf16 (+ C fp32 kept)
  gemm_tile<4>(A, pw + PW_CS, w * 4, lane, acc);
  {
    const int col = lane & 15, rb = (lane >> 4) * 4;
#pragma unroll
    for (int nt = 0; nt < 4; ++nt) {
      const int dim = (w * 4 + nt) * 16 + col;
      const float bj = b_cs[dim];
#pragma unroll
      for (int i = 0; i < 4; ++i) {
        const int tok = tok0 + rb + i;
        const float tv = (tok < NTOK) ? tgt[(size_t)tok * DM + dim] : 0.f;
        C[(rb + i) * CS + dim] = acc[nt][i] + bj + tv;
      }
    }
  }
  __syncthreads();
  ln_c_to_a<true>(C, A, g1, be1, w, lane);
  __syncthreads();

  // 8. u = gelu(t @ w1 + b1); y = t + u (element-wise in-place on C)
  gemm_tile<4>(A, pw + PW_W1, w * 4, lane, acc);
  {
    const int col = lane & 15, rb = (lane >> 4) * 4;
#pragma unroll
    for (int nt = 0; nt < 4; ++nt) {
      const int dim = (w * 4 + nt) * 16 + col;
      const float bj = b1[dim];
#pragma unroll
      for (int i = 0; i < 4; ++i) {
        const float x = acc[nt][i] + bj;
        const float gel = 0.5f * x * (1.0f + erff(x * 0.70710678118654752f));
        const int ci = (rb + i) * CS + dim;
        C[ci] = C[ci] + gel;   // one writer per element; no other reader until sync
      }
    }
  }
  __syncthreads();

  // 9. LN2 -> out (fp32, coalesced float4 stores)
#pragma unroll
  for (int tt = 0; tt < 4; ++tt) {
    const int t = w * 4 + tt, tok = tok0 + t;
    float4 v = *reinterpret_cast<float4*>(&C[t * CS + lane * 4]);
    float s = v.x + v.y + v.z + v.w;
#pragma unroll
    for (int o = 32; o; o >>= 1) s += __shfl_xor(s, o);
    const float m = s * (1.f / 256.f);
    const float d0 = v.x - m, d1 = v.y - m, d2 = v.z - m, d3 = v.w - m;
    float s2 = d0 * d0 + d1 * d1 + d2 * d2 + d3 * d3;
#pragma unroll
    for (int o = 32; o; o >>= 1) s2 += __shfl_xor(s2, o);
    const float rs = rsqrtf(s2 * (1.f / 256.f) + 1e-5f);
    if (tok < NTOK) {
      const float4 gg = *reinterpret_cast<const float4*>(&g2[lane * 4]);
      const float4 bb = *reinterpret_cast<const float4*>(&be2[lane * 4]);
      float4 o4;
      o4.x = d0 * rs * gg.x + bb.x; o4.y = d1 * rs * gg.y + bb.y;
      o4.z = d2 * rs * gg.z + bb.z; o4.w = d3 * rs * gg.w + bb.w;
      *reinterpret_cast<float4*>(&out[(size_t)tok * DM + lane * 4]) = o4;
    }
  }
}

// ---------------- launch ----------------

extern "C" void kernel_launch(void* const* d_in, const int* in_sizes, int n_in,
                              void* d_out, int out_size, void* d_ws, size_t ws_size,
                              hipStream_t stream) {
  const float* tgt    = (const float*)d_in[0];
  const float* qp     = (const float*)d_in[1];
  const float* ref    = (const float*)d_in[2];
  const float* src    = (const float*)d_in[3];
  const float* w_ds   = (const float*)d_in[6];
  const float* b_ds   = (const float*)d_in[7];
  const float* g_ds   = (const float*)d_in[8];
  const float* be_ds  = (const float*)d_in[9];
  const float* w_off  = (const float*)d_in[10];
  const float* b_off  = (const float*)d_in[11];
  const float* w_attn = (const float*)d_in[12];
  const float* b_attn = (const float*)d_in[13];
  const float* w_val  = (const float*)d_in[14];
  const float* b_val  = (const float*)d_in[15];
  const float* w_out  = (const float*)d_in[16];
  const float* b_out  = (const float*)d_in[17];
  const float* w_cs   = (const float*)d_in[18];
  const float* b_cs   = (const float*)d_in[19];
  const float* g1     = (const float*)d_in[20];
  const float* be1    = (const float*)d_in[21];
  const float* w1     = (const float*)d_in[22];
  const float* b1     = (const float*)d_in[23];
  const float* g2     = (const float*)d_in[24];
  const float* be2    = (const float*)d_in[25];

  ushort* pw    = (ushort*)d_ws;                              // 832 KB packed bf16 weights
  ushort* value = (ushort*)((char*)d_ws + VALUE_WS_OFF);      // 11.5 MB bf16 value
  float*  out   = (float*)d_out;

  const int nblk = (NTOK + TT - 1) / TT;  // 1407
  hipLaunchKernelGGL(k_pack, dim3(208), dim3(256), 0, stream,
                     w_ds, w_val, w_off, w_out, w_cs, w1, w_attn, pw);
  hipLaunchKernelGGL(k_value, dim3(nblk), dim3(256), 0, stream,
                     src, pw, b_ds, g_ds, be_ds, b_val, value);
  hipLaunchKernelGGL(k_attn, dim3(nblk), dim3(256), 0, stream,
                     tgt, qp, ref, pw, b_off, b_attn, value,
                     b_out, b_cs, g1, be1, b1, g2, be2, out);
}

// Round 3
// 164.518 us; speedup vs baseline: 4.2709x; 1.2296x over previous
//
#include <hip/hip_runtime.h>
#include <hip/hip_fp16.h>
#include <math.h>

// Problem constants (fixed by setup_inputs)
#define DM   256
#define LQ   11253
#define NTOK (2*LQ)
#define TT   16      // tokens per block
#define AS   264     // ushorts per A (bf16) LDS row: 256 + 8 pad
#define CS   260     // floats per C (fp32) LDS row: 256 + 4 pad
#define AWS  132     // floats per AW row: 128 + 4 pad

typedef __attribute__((ext_vector_type(8))) short bf16x8;  // 8 bf16 in 4 VGPRs
typedef __attribute__((ext_vector_type(4))) float f32x4;

// packed-weight offsets (ushort units)
#define PW_DS  0
#define PW_VAL 65536
#define PW_OFF 131072
#define PW_OUT 196608
#define PW_CS  262144
#define PW_W1  327680
#define PW_ATT 393216
#define VALUE_WS_OFF (1u<<20)  // value bf16 buffer at +1 MiB in d_ws

// k_attn LDS layout (bytes) -- lifetime-aliased regions:
//  phase 1-4:  A(q)[0,8448) | C(offs)[8448,25088) | AW[25088,33536)
//  precompute: S[0,24576) over A+C (C/AW pre-read to regs, double sync)
//  gather:     reads S, writes ATT[24576,33024) over dead C-tail/AW
//  tail GEMMs: C2[0,16640) over dead S | A2[16640,25088) | ATT read then dead
#define OFF_A    0
#define OFF_C    8448
#define OFF_AW   25088
#define OFF_S    0
#define OFF_ATT  24576
#define OFF_C2   0
#define OFF_A2   16640
#define LDS_SZ   33536

// ---------------- small helpers ----------------

__device__ __forceinline__ ushort f2b(float x) {   // fp32 -> bf16 (RNE)
  union { float f; unsigned u; } c; c.f = x;
  unsigned u = c.u + 0x7fffu + ((c.u >> 16) & 1u);
  return (ushort)(u >> 16);
}
__device__ __forceinline__ float blo(unsigned u) { // low bf16 of a pair -> fp32
  union { unsigned u; float f; } c; c.u = u << 16; return c.f;
}
__device__ __forceinline__ float bhi(unsigned u) { // high bf16 of a pair -> fp32
  union { unsigned u; float f; } c; c.u = u & 0xffff0000u; return c.f;
}
__device__ __forceinline__ int clampr(int v) {     // clamp row into value buffer
  return min(max(v, 0), NTOK - 1);
}

// ---------------- weight pack: fp32 [K][N] -> bf16 MFMA B-fragments ----------

__global__ __launch_bounds__(256) void k_pack(
    const float* __restrict__ w0, const float* __restrict__ w1,
    const float* __restrict__ w2, const float* __restrict__ w3,
    const float* __restrict__ w4, const float* __restrict__ w5,
    const float* __restrict__ wa, ushort* __restrict__ out) {
  const int gid = blockIdx.x * 256 + threadIdx.x;
  const float* W; int N; size_t obase; int local;
  if (gid < 6 * 8192) {
    const int wi = gid >> 13; local = gid & 8191; N = 256;
    obase = (size_t)wi * 65536;
    W = (wi == 0) ? w0 : (wi == 1) ? w1 : (wi == 2) ? w2
      : (wi == 3) ? w3 : (wi == 4) ? w4 : w5;
  } else {
    local = gid - 6 * 8192; N = 128; obase = PW_ATT; W = wa;
  }
  const int l = local & 63, f = local >> 6;
  const int kt = f & 7, nt = f >> 3;
  const int k0 = kt * 32 + (l >> 4) * 8, col = nt * 16 + (l & 15);
  ushort v[8];
#pragma unroll
  for (int e = 0; e < 8; ++e) v[e] = f2b(W[(size_t)(k0 + e) * N + col]);
  *reinterpret_cast<uint4*>(&out[obase + (size_t)local * 8]) =
      *reinterpret_cast<const uint4*>(v);
}

// ---------------- GEMM tile helpers ----------------

template<int NTW>
__device__ __forceinline__ void gemm_tile(const ushort* __restrict__ A,
                                          const ushort* __restrict__ Bp,
                                          int ntBase, int lane,
                                          f32x4 (&acc)[NTW]) {
  const int r = lane & 15, hk = lane >> 4;
  const ushort* arow = A + r * AS + hk * 8;
#pragma unroll
  for (int nt = 0; nt < NTW; ++nt) acc[nt] = (f32x4){0.f, 0.f, 0.f, 0.f};
#pragma unroll
  for (int kt = 0; kt < 8; ++kt) {
    const bf16x8 a = *(const bf16x8*)(arow + kt * 32);
#pragma unroll
    for (int nt = 0; nt < NTW; ++nt) {
      const bf16x8 b = *(const bf16x8*)(Bp + ((size_t)((ntBase + nt) * 8 + kt) * 64 + lane) * 8);
      acc[nt] = __builtin_amdgcn_mfma_f32_16x16x32_bf16(a, b, acc[nt], 0, 0, 0);
    }
  }
}

template<int NTW>
__device__ __forceinline__ void acc_to_c(const f32x4 (&acc)[NTW], float* C,
                                         const float* __restrict__ bias,
                                         int ntBase, int lane, int rowStride) {
  const int col = lane & 15, rb = (lane >> 4) * 4;
#pragma unroll
  for (int nt = 0; nt < NTW; ++nt) {
    const int dim = (ntBase + nt) * 16 + col;
    const float bj = bias[dim];
#pragma unroll
    for (int i = 0; i < 4; ++i) C[(rb + i) * rowStride + dim] = acc[nt][i] + bj;
  }
}

template<bool ADD>
__device__ __forceinline__ void load_to_A(const float* __restrict__ X,
                                          const float* __restrict__ Y,
                                          int tok0, ushort* A, int w, int lane) {
#pragma unroll
  for (int tt = 0; tt < 4; ++tt) {
    const int t = w * 4 + tt, tok = tok0 + t;
    float4 v = make_float4(0.f, 0.f, 0.f, 0.f);
    if (tok < NTOK) {
      v = *reinterpret_cast<const float4*>(&X[(size_t)tok * DM + lane * 4]);
      if (ADD) {
        const float4 y = *reinterpret_cast<const float4*>(&Y[(size_t)tok * DM + lane * 4]);
        v.x += y.x; v.y += y.y; v.z += y.z; v.w += y.w;
      }
    }
    ushort4 b; b.x = f2b(v.x); b.y = f2b(v.y); b.z = f2b(v.z); b.w = f2b(v.w);
    *reinterpret_cast<ushort4*>(&A[t * AS + lane * 4]) = b;
  }
}

template<bool WRITEBACK>
__device__ __forceinline__ void ln_c_to_a(float* C, ushort* A,
                                          const float* __restrict__ g,
                                          const float* __restrict__ be,
                                          int w, int lane) {
#pragma unroll
  for (int tt = 0; tt < 4; ++tt) {
    const int t = w * 4 + tt;
    float4 v = *reinterpret_cast<float4*>(&C[t * CS + lane * 4]);
    float s = v.x + v.y + v.z + v.w;
#pragma unroll
    for (int o = 32; o; o >>= 1) s += __shfl_xor(s, o);
    const float m = s * (1.f / 256.f);
    const float d0 = v.x - m, d1 = v.y - m, d2 = v.z - m, d3 = v.w - m;
    float s2 = d0 * d0 + d1 * d1 + d2 * d2 + d3 * d3;
#pragma unroll
    for (int o = 32; o; o >>= 1) s2 += __shfl_xor(s2, o);
    const float rs = rsqrtf(s2 * (1.f / 256.f) + 1e-5f);
    const float4 gg = *reinterpret_cast<const float4*>(&g[lane * 4]);
    const float4 bb = *reinterpret_cast<const float4*>(&be[lane * 4]);
    float4 o4;
    o4.x = d0 * rs * gg.x + bb.x; o4.y = d1 * rs * gg.y + bb.y;
    o4.z = d2 * rs * gg.z + bb.z; o4.w = d3 * rs * gg.w + bb.w;
    ushort4 ob; ob.x = f2b(o4.x); ob.y = f2b(o4.y); ob.z = f2b(o4.z); ob.w = f2b(o4.w);
    *reinterpret_cast<ushort4*>(&A[t * AS + lane * 4]) = ob;
    if (WRITEBACK) *reinterpret_cast<float4*>(&C[t * CS + lane * 4]) = o4;
  }
}

__device__ __forceinline__ void c_to_a(const float* C, ushort* A, int w, int lane) {
#pragma unroll
  for (int tt = 0; tt < 4; ++tt) {
    const int t = w * 4 + tt;
    const float4 v = *reinterpret_cast<const float4*>(&C[t * CS + lane * 4]);
    ushort4 ob; ob.x = f2b(v.x); ob.y = f2b(v.y); ob.z = f2b(v.z); ob.w = f2b(v.w);
    *reinterpret_cast<ushort4*>(&A[t * AS + lane * 4]) = ob;
  }
}

// ---------------- kernel A: value = LN(src @ w_ds) @ w_val  (bf16 out) -------

__global__ __launch_bounds__(256) void k_value(
    const float* __restrict__ src, const ushort* __restrict__ pw,
    const float* __restrict__ b_ds, const float* __restrict__ g_ds,
    const float* __restrict__ be_ds, const float* __restrict__ b_val,
    ushort* __restrict__ value) {
  __shared__ __align__(16) ushort A[TT * AS];
  __shared__ __align__(16) float  C[TT * CS];
  const int tid = threadIdx.x, w = tid >> 6, lane = tid & 63;
  const int tok0 = blockIdx.x * TT;

  load_to_A<false>(src, nullptr, tok0, A, w, lane);
  __syncthreads();
  f32x4 acc[4];
  gemm_tile<4>(A, pw + PW_DS, w * 4, lane, acc);
  acc_to_c<4>(acc, C, b_ds, w * 4, lane, CS);
  __syncthreads();
  ln_c_to_a<false>(C, A, g_ds, be_ds, w, lane);
  __syncthreads();
  gemm_tile<4>(A, pw + PW_VAL, w * 4, lane, acc);
  acc_to_c<4>(acc, C, b_val, w * 4, lane, CS);
  __syncthreads();
#pragma unroll
  for (int tt = 0; tt < 4; ++tt) {
    const int t = w * 4 + tt, tok = tok0 + t;
    if (tok < NTOK) {
      const float4 v = *reinterpret_cast<const float4*>(&C[t * CS + lane * 4]);
      ushort4 b; b.x = f2b(v.x); b.y = f2b(v.y); b.z = f2b(v.z); b.w = f2b(v.w);
      *reinterpret_cast<ushort4*>(&value[(size_t)tok * DM + lane * 4]) = b;
    }
  }
}

// ---------------- kernel B: deform-attn + FFN tail ----------------

__global__ __launch_bounds__(256, 4) void k_attn(
    const float* __restrict__ tgt, const float* __restrict__ qp,
    const float* __restrict__ ref, const ushort* __restrict__ pw,
    const float* __restrict__ b_off, const float* __restrict__ b_attn,
    const ushort* __restrict__ value,
    const float* __restrict__ b_out, const float* __restrict__ b_cs,
    const float* __restrict__ g1, const float* __restrict__ be1,
    const float* __restrict__ b1,
    const float* __restrict__ g2, const float* __restrict__ be2,
    float* __restrict__ out) {
  __shared__ __align__(16) unsigned char LDSB[LDS_SZ];
  ushort* A  = (ushort*)(LDSB + OFF_A);
  float*  C  = (float*) (LDSB + OFF_C);
  float*  AW = (float*) (LDSB + OFF_AW);
  const int tid = threadIdx.x, w = tid >> 6, lane = tid & 63;

  // bijective XCD-chunk swizzle (nwg = 1407 = 7*176 + 175)
  const int bid = blockIdx.x;
  const int xcd = bid & 7, pos = bid >> 3;
  const int swz = (xcd < 7 ? xcd * 176 : 7 * 176) + pos;
  const int tok0 = swz * TT;

  // 1. q = tgt + query_pos -> A bf16
  load_to_A<true>(tgt, qp, tok0, A, w, lane);
  __syncthreads();

  f32x4 acc[4];
  // 2. offsets GEMM -> C; logits GEMM -> AW
  gemm_tile<4>(A, pw + PW_OFF, w * 4, lane, acc);
  acc_to_c<4>(acc, C, b_off, w * 4, lane, CS);
  {
    f32x4 a2[2];
    gemm_tile<2>(A, pw + PW_ATT, w * 2, lane, a2);
    acc_to_c<2>(a2, AW, b_attn, w * 2, lane, AWS);
  }
  __syncthreads();

  // 3. softmax over 16 per (token, head)
  if (tid < TT * 8) {
    const int t = tid >> 3, h = tid & 7;
    float* a = &AW[t * AWS + h * 16];
    float m = a[0];
#pragma unroll
    for (int i = 1; i < 16; ++i) m = fmaxf(m, a[i]);
    float s = 0.f, e[16];
#pragma unroll
    for (int i = 0; i < 16; ++i) { e[i] = expf(a[i] - m); s += e[i]; }
    const float inv = 1.0f / s;
#pragma unroll
    for (int i = 0; i < 16; ++i) a[i] = e[i] * inv;
  }
  __syncthreads();

  // 4. precompute sample descriptors: {base row, 4 aw-folded half weights}
  //    thread -> token tl = tid>>4, slot c = tid&15 (fixed l,p; i iterates heads)
  {
    const int tl = tid >> 4, c = tid & 15;
    const int l = (c >> 2) & 3;
    const int Wl  = (l == 0) ? 92 : (l == 1) ? 46 : (l == 2) ? 23 : 12;
    const int lsi = (l == 0) ? 0  : (l == 1) ? 8464 : (l == 2) ? 10580 : 11109;
    const float fW = (float)Wl;
    const int tok = tok0 + tl;
    const int tokc = (tok < NTOK) ? tok : (NTOK - 1);
    const float refx = ref[(size_t)tokc * 8 + l * 2 + 0];
    const float refy = ref[(size_t)tokc * 8 + l * 2 + 1];
    const int rbas = ((tok >= LQ) ? LQ : 0) + lsi;
    const float vmask = (tok < NTOK) ? 1.f : 0.f;
    int sbv[8]; unsigned sw01[8], sw23[8];
#pragma unroll
    for (int i = 0; i < 8; ++i) {
      const int pt = i * 16 + c;
      const float ox = C[tl * CS + pt * 2 + 0];
      const float oy = C[tl * CS + pt * 2 + 1];
      const float aw = AW[tl * AWS + pt] * vmask;
      const float x = fmaf(refx, fW, ox) - 0.5f;
      const float y = fmaf(refy, fW, oy) - 0.5f;
      const float x0f = floorf(x), y0f = floorf(y);
      const int x0 = (int)x0f, y0 = (int)y0f;
      const float fx = x - x0f, fy = y - y0f;
      const float gx = 1.f - fx, gy = 1.f - fy;
      const float wx0 = ((x0 >= 0) & (x0 < Wl)) ? gx : 0.f;
      const float wx1 = ((x0 >= -1) & (x0 < Wl - 1)) ? fx : 0.f;
      const float wy0 = (((y0 >= 0) & (y0 < Wl)) ? gy : 0.f) * aw;
      const float wy1 = (((y0 >= -1) & (y0 < Wl - 1)) ? fy : 0.f) * aw;
      const __half2 h01 = __floats2half2_rn(wx0 * wy0, wx1 * wy0);
      const __half2 h23 = __floats2half2_rn(wx0 * wy1, wx1 * wy1);
      sbv[i]  = rbas + y0 * Wl + x0;
      sw01[i] = *reinterpret_cast<const unsigned*>(&h01);
      sw23[i] = *reinterpret_cast<const unsigned*>(&h23);
    }
    __syncthreads();   // every thread done reading C/AW
    unsigned* S = (unsigned*)(LDSB + OFF_S);
#pragma unroll
    for (int i = 0; i < 8; ++i) {
      const int so = (tl * 128 + i * 16 + c) * 3;
      S[so] = (unsigned)sbv[i]; S[so + 1] = sw01[i]; S[so + 2] = sw23[i];
    }
  }
  __syncthreads();

  // 5. gather: branch-free blend using precomputed descriptors
  {
    const int hh = (tid >> 4) & 7;
    const int d2 = tid & 15;
    const int cix = hh * 16 + d2;          // uint column within a value row
    const int cdim = hh * 32 + d2 * 2;     // bf16 dim
    const int thalf = (tid >> 7) * 8;
    const unsigned* __restrict__ vbuf = (const unsigned*)value;
    const unsigned* S = (const unsigned*)(LDSB + OFF_S);
    ushort* ATT = (ushort*)(LDSB + OFF_ATT);
#pragma unroll 1
    for (int ti = 0; ti < 8; ++ti) {
      const int t = thalf + ti;
      float o0 = 0.f, o1 = 0.f;
      const int sb = (t * 128 + hh * 16) * 3;
#pragma unroll
      for (int l = 0; l < 4; ++l) {
        const int Wl = (l == 0) ? 92 : (l == 1) ? 46 : (l == 2) ? 23 : 12;
#pragma unroll
        for (int p = 0; p < 4; ++p) {
          const int so = sb + (l * 4 + p) * 3;
          const int base = (int)S[so];
          const unsigned uw01 = S[so + 1], uw23 = S[so + 2];
          const int r00 = clampr(base),      r10 = clampr(base + 1);
          const int r01 = clampr(base + Wl), r11 = clampr(base + Wl + 1);
          const unsigned u00 = vbuf[(size_t)r00 * 128 + cix];
          const unsigned u10 = vbuf[(size_t)r10 * 128 + cix];
          const unsigned u01 = vbuf[(size_t)r01 * 128 + cix];
          const unsigned u11 = vbuf[(size_t)r11 * 128 + cix];
          const __half2 hw01 = *reinterpret_cast<const __half2*>(&uw01);
          const __half2 hw23 = *reinterpret_cast<const __half2*>(&uw23);
          const float w00 = __low2float(hw01), w10 = __high2float(hw01);
          const float w01 = __low2float(hw23), w11 = __high2float(hw23);
          o0 = fmaf(w00, blo(u00), o0); o1 = fmaf(w00, bhi(u00), o1);
          o0 = fmaf(w10, blo(u10), o0); o1 = fmaf(w10, bhi(u10), o1);
          o0 = fmaf(w01, blo(u01), o0); o1 = fmaf(w01, bhi(u01), o1);
          o0 = fmaf(w11, blo(u11), o0); o1 = fmaf(w11, bhi(u11), o1);
        }
      }
      const unsigned u = (unsigned)f2b(o0) | ((unsigned)f2b(o1) << 16);
      *reinterpret_cast<unsigned*>(&ATT[(size_t)t * AS + cdim]) = u;
    }
  }
  __syncthreads();

  // 6. t2a = attn @ w_out + b_out -> C2 (over dead S); then -> A2 bf16
  {
    const ushort* ATT = (const ushort*)(LDSB + OFF_ATT);
    float* C2 = (float*)(LDSB + OFF_C2);
    ushort* A2 = (ushort*)(LDSB + OFF_A2);
    gemm_tile<4>(ATT, pw + PW_OUT, w * 4, lane, acc);
    acc_to_c<4>(acc, C2, b_out, w * 4, lane, CS);
    __syncthreads();
    c_to_a(C2, A2, w, lane);
  }
  __syncthreads();

  // 7. t2 = t2a @ w_cs + b_cs + tgt -> C2; LN1 -> A2 bf16 (+ C2 fp32 kept)
  {
    ushort* A2 = (ushort*)(LDSB + OFF_A2);
    float* C2 = (float*)(LDSB + OFF_C2);
    gemm_tile<4>(A2, pw + PW_CS, w * 4, lane, acc);
    const int col = lane & 15, rb = (lane >> 4) * 4;
#pragma unroll
    for (int nt = 0; nt < 4; ++nt) {
      const int dim = (w * 4 + nt) * 16 + col;
      const float bj = b_cs[dim];
#pragma unroll
      for (int i = 0; i < 4; ++i) {
        const int tok = tok0 + rb + i;
        const float tv = (tok < NTOK) ? tgt[(size_t)tok * DM + dim] : 0.f;
        C2[(rb + i) * CS + dim] = acc[nt][i] + bj + tv;
      }
    }
    __syncthreads();
    ln_c_to_a<true>(C2, A2, g1, be1, w, lane);
  }
  __syncthreads();

  // 8. u = gelu(t @ w1 + b1); y = t + u (in-place on C2)
  {
    ushort* A2 = (ushort*)(LDSB + OFF_A2);
    float* C2 = (float*)(LDSB + OFF_C2);
    gemm_tile<4>(A2, pw + PW_W1, w * 4, lane, acc);
    const int col = lane & 15, rb = (lane >> 4) * 4;
#pragma unroll
    for (int nt = 0; nt < 4; ++nt) {
      const int dim = (w * 4 + nt) * 16 + col;
      const float bj = b1[dim];
#pragma unroll
      for (int i = 0; i < 4; ++i) {
        const float x = acc[nt][i] + bj;
        const float gel = 0.5f * x * (1.0f + erff(x * 0.70710678118654752f));
        const int ci = (rb + i) * CS + dim;
        C2[ci] = C2[ci] + gel;
      }
    }
  }
  __syncthreads();

  // 9. LN2 -> out
  {
    float* C2 = (float*)(LDSB + OFF_C2);
#pragma unroll
    for (int tt = 0; tt < 4; ++tt) {
      const int t = w * 4 + tt, tok = tok0 + t;
      float4 v = *reinterpret_cast<float4*>(&C2[t * CS + lane * 4]);
      float s = v.x + v.y + v.z + v.w;
#pragma unroll
      for (int o = 32; o; o >>= 1) s += __shfl_xor(s, o);
      const float m = s * (1.f / 256.f);
      const float d0 = v.x - m, d1 = v.y - m, d2 = v.z - m, d3 = v.w - m;
      float s2 = d0 * d0 + d1 * d1 + d2 * d2 + d3 * d3;
#pragma unroll
      for (int o = 32; o; o >>= 1) s2 += __shfl_xor(s2, o);
      const float rs = rsqrtf(s2 * (1.f / 256.f) + 1e-5f);
      if (tok < NTOK) {
        const float4 gg = *reinterpret_cast<const float4*>(&g2[lane * 4]);
        const float4 bb = *reinterpret_cast<const float4*>(&be2[lane * 4]);
        float4 o4;
        o4.x = d0 * rs * gg.x + bb.x; o4.y = d1 * rs * gg.y + bb.y;
        o4.z = d2 * rs * gg.z + bb.z; o4.w = d3 * rs * gg.w + bb.w;
        *reinterpret_cast<float4*>(&out[(size_t)tok * DM + lane * 4]) = o4;
      }
    }
  }
}

// ---------------- launch ----------------

extern "C" void kernel_launch(void* const* d_in, const int* in_sizes, int n_in,
                              void* d_out, int out_size, void* d_ws, size_t ws_size,
                              hipStream_t stream) {
  const float* tgt    = (const float*)d_in[0];
  const float* qp     = (const float*)d_in[1];
  const float* ref    = (const float*)d_in[2];
  const float* src    = (const float*)d_in[3];
  const float* w_ds   = (const float*)d_in[6];
  const float* b_ds   = (const float*)d_in[7];
  const float* g_ds   = (const float*)d_in[8];
  const float* be_ds  = (const float*)d_in[9];
  const float* w_off  = (const float*)d_in[10];
  const float* b_off  = (const float*)d_in[11];
  const float* w_attn = (const float*)d_in[12];
  const float* b_attn = (const float*)d_in[13];
  const float* w_val  = (const float*)d_in[14];
  const float* b_val  = (const float*)d_in[15];
  const float* w_out  = (const float*)d_in[16];
  const float* b_out  = (const float*)d_in[17];
  const float* w_cs   = (const float*)d_in[18];
  const float* b_cs   = (const float*)d_in[19];
  const float* g1     = (const float*)d_in[20];
  const float* be1    = (const float*)d_in[21];
  const float* w1     = (const float*)d_in[22];
  const float* b1     = (const float*)d_in[23];
  const float* g2     = (const float*)d_in[24];
  const float* be2    = (const float*)d_in[25];

  ushort* pw    = (ushort*)d_ws;
  ushort* value = (ushort*)((char*)d_ws + VALUE_WS_OFF);
  float*  out   = (float*)d_out;

  const int nblk = (NTOK + TT - 1) / TT;  // 1407
  hipLaunchKernelGGL(k_pack, dim3(208), dim3(256), 0, stream,
                     w_ds, w_val, w_off, w_out, w_cs, w1, w_attn, pw);
  hipLaunchKernelGGL(k_value, dim3(nblk), dim3(256), 0, stream,
                     src, pw, b_ds, g_ds, be_ds, b_val, value);
  hipLaunchKernelGGL(k_attn, dim3(nblk), dim3(256), 0, stream,
                     tgt, qp, ref, pw, b_off, b_attn, value,
                     b_out, b_cs, g1, be1, b1, g2, be2, out);
}

// Round 4
// 162.573 us; speedup vs baseline: 4.3220x; 1.0120x over previous
//
#include <hip/hip_runtime.h>
#include <hip/hip_fp16.h>
#include <math.h>

// Problem constants (fixed by setup_inputs)
#define DM    256
#define LQ    11253
#define NTOK  (2*LQ)        // 22506
#define TT    16            // tokens per block (GEMM kernels)
#define NTOKP 22512         // 1407*16 padded token count for descriptor arrays
#define AS    264           // ushorts per A (bf16) LDS row: 256 + 8 pad
#define CS    260           // floats per C (fp32) LDS row: 256 + 4 pad
#define AWS   132           // floats per AW row: 128 + 4 pad

typedef __attribute__((ext_vector_type(8))) short bf16x8;
typedef __attribute__((ext_vector_type(4))) float f32x4;

// packed-weight offsets (ushort units)
#define PW_DS  0
#define PW_VAL 65536
#define PW_OFF 131072
#define PW_OUT 196608
#define PW_CS  262144
#define PW_W1  327680
#define PW_ATT 393216
// ws layout (bytes): pw [0, 852K) | xy [1MiB, ~12.6MB) | aw [12MiB, ~18.3MB)
#define XY_WS_OFF (1u<<20)
#define AW_WS_OFF (12u<<20)
// d_out layout: per token a 1024B slot: ATT bf16 [0,512) | value bf16 [512,1024)

// ---------------- small helpers ----------------

__device__ __forceinline__ ushort f2b(float x) {   // fp32 -> bf16 (RNE)
  union { float f; unsigned u; } c; c.f = x;
  unsigned u = c.u + 0x7fffu + ((c.u >> 16) & 1u);
  return (ushort)(u >> 16);
}
__device__ __forceinline__ float blo(unsigned u) {
  union { unsigned u; float f; } c; c.u = u << 16; return c.f;
}
__device__ __forceinline__ float bhi(unsigned u) {
  union { unsigned u; float f; } c; c.u = u & 0xffff0000u; return c.f;
}
__device__ __forceinline__ int clampr(int v) { return min(max(v, 0), NTOK - 1); }

// ---------------- weight pack: fp32 [K][N] -> bf16 MFMA B-fragments ----------

__global__ __launch_bounds__(256) void k_pack(
    const float* __restrict__ w0, const float* __restrict__ w1,
    const float* __restrict__ w2, const float* __restrict__ w3,
    const float* __restrict__ w4, const float* __restrict__ w5,
    const float* __restrict__ wa, ushort* __restrict__ out) {
  const int gid = blockIdx.x * 256 + threadIdx.x;
  const float* W; int N; size_t obase; int local;
  if (gid < 6 * 8192) {
    const int wi = gid >> 13; local = gid & 8191; N = 256;
    obase = (size_t)wi * 65536;
    W = (wi == 0) ? w0 : (wi == 1) ? w1 : (wi == 2) ? w2
      : (wi == 3) ? w3 : (wi == 4) ? w4 : w5;
  } else {
    local = gid - 6 * 8192; N = 128; obase = PW_ATT; W = wa;
  }
  const int l = local & 63, f = local >> 6;
  const int kt = f & 7, nt = f >> 3;
  const int k0 = kt * 32 + (l >> 4) * 8, col = nt * 16 + (l & 15);
  ushort v[8];
#pragma unroll
  for (int e = 0; e < 8; ++e) v[e] = f2b(W[(size_t)(k0 + e) * N + col]);
  *reinterpret_cast<uint4*>(&out[obase + (size_t)local * 8]) =
      *reinterpret_cast<const uint4*>(v);
}

// ---------------- GEMM tile helpers ----------------

template<int NTW>
__device__ __forceinline__ void gemm_tile(const ushort* __restrict__ A,
                                          const ushort* __restrict__ Bp,
                                          int ntBase, int lane,
                                          f32x4 (&acc)[NTW]) {
  const int r = lane & 15, hk = lane >> 4;
  const ushort* arow = A + r * AS + hk * 8;
#pragma unroll
  for (int nt = 0; nt < NTW; ++nt) acc[nt] = (f32x4){0.f, 0.f, 0.f, 0.f};
#pragma unroll
  for (int kt = 0; kt < 8; ++kt) {
    const bf16x8 a = *(const bf16x8*)(arow + kt * 32);
#pragma unroll
    for (int nt = 0; nt < NTW; ++nt) {
      const bf16x8 b = *(const bf16x8*)(Bp + ((size_t)((ntBase + nt) * 8 + kt) * 64 + lane) * 8);
      acc[nt] = __builtin_amdgcn_mfma_f32_16x16x32_bf16(a, b, acc[nt], 0, 0, 0);
    }
  }
}

template<int NTW>
__device__ __forceinline__ void acc_to_c(const f32x4 (&acc)[NTW], float* C,
                                         const float* __restrict__ bias,
                                         int ntBase, int lane, int rowStride) {
  const int col = lane & 15, rb = (lane >> 4) * 4;
#pragma unroll
  for (int nt = 0; nt < NTW; ++nt) {
    const int dim = (ntBase + nt) * 16 + col;
    const float bj = bias[dim];
#pragma unroll
    for (int i = 0; i < 4; ++i) C[(rb + i) * rowStride + dim] = acc[nt][i] + bj;
  }
}

template<bool ADD>
__device__ __forceinline__ void load_to_A(const float* __restrict__ X,
                                          const float* __restrict__ Y,
                                          int tok0, ushort* A, int w, int lane) {
#pragma unroll
  for (int tt = 0; tt < 4; ++tt) {
    const int t = w * 4 + tt, tok = tok0 + t;
    float4 v = make_float4(0.f, 0.f, 0.f, 0.f);
    if (tok < NTOK) {
      v = *reinterpret_cast<const float4*>(&X[(size_t)tok * DM + lane * 4]);
      if (ADD) {
        const float4 y = *reinterpret_cast<const float4*>(&Y[(size_t)tok * DM + lane * 4]);
        v.x += y.x; v.y += y.y; v.z += y.z; v.w += y.w;
      }
    }
    ushort4 b; b.x = f2b(v.x); b.y = f2b(v.y); b.z = f2b(v.z); b.w = f2b(v.w);
    *reinterpret_cast<ushort4*>(&A[t * AS + lane * 4]) = b;
  }
}

template<bool WRITEBACK>
__device__ __forceinline__ void ln_c_to_a(float* C, ushort* A,
                                          const float* __restrict__ g,
                                          const float* __restrict__ be,
                                          int w, int lane) {
#pragma unroll
  for (int tt = 0; tt < 4; ++tt) {
    const int t = w * 4 + tt;
    float4 v = *reinterpret_cast<float4*>(&C[t * CS + lane * 4]);
    float s = v.x + v.y + v.z + v.w;
#pragma unroll
    for (int o = 32; o; o >>= 1) s += __shfl_xor(s, o);
    const float m = s * (1.f / 256.f);
    const float d0 = v.x - m, d1 = v.y - m, d2 = v.z - m, d3 = v.w - m;
    float s2 = d0 * d0 + d1 * d1 + d2 * d2 + d3 * d3;
#pragma unroll
    for (int o = 32; o; o >>= 1) s2 += __shfl_xor(s2, o);
    const float rs = rsqrtf(s2 * (1.f / 256.f) + 1e-5f);
    const float4 gg = *reinterpret_cast<const float4*>(&g[lane * 4]);
    const float4 bb = *reinterpret_cast<const float4*>(&be[lane * 4]);
    float4 o4;
    o4.x = d0 * rs * gg.x + bb.x; o4.y = d1 * rs * gg.y + bb.y;
    o4.z = d2 * rs * gg.z + bb.z; o4.w = d3 * rs * gg.w + bb.w;
    ushort4 ob; ob.x = f2b(o4.x); ob.y = f2b(o4.y); ob.z = f2b(o4.z); ob.w = f2b(o4.w);
    *reinterpret_cast<ushort4*>(&A[t * AS + lane * 4]) = ob;
    if (WRITEBACK) *reinterpret_cast<float4*>(&C[t * CS + lane * 4]) = o4;
  }
}

__device__ __forceinline__ void c_to_a(const float* C, ushort* A, int w, int lane) {
#pragma unroll
  for (int tt = 0; tt < 4; ++tt) {
    const int t = w * 4 + tt;
    const float4 v = *reinterpret_cast<const float4*>(&C[t * CS + lane * 4]);
    ushort4 ob; ob.x = f2b(v.x); ob.y = f2b(v.y); ob.z = f2b(v.z); ob.w = f2b(v.w);
    *reinterpret_cast<ushort4*>(&A[t * AS + lane * 4]) = ob;
  }
}

// ------------- kernel 1: value = LN(src @ w_ds) @ w_val -> d_out slots -------

__global__ __launch_bounds__(256) void k_value(
    const float* __restrict__ src, const ushort* __restrict__ pw,
    const float* __restrict__ b_ds, const float* __restrict__ g_ds,
    const float* __restrict__ be_ds, const float* __restrict__ b_val,
    unsigned char* __restrict__ dout) {
  __shared__ __align__(16) ushort A[TT * AS];
  __shared__ __align__(16) float  C[TT * CS];
  const int tid = threadIdx.x, w = tid >> 6, lane = tid & 63;
  const int tok0 = blockIdx.x * TT;

  load_to_A<false>(src, nullptr, tok0, A, w, lane);
  __syncthreads();
  f32x4 acc[4];
  gemm_tile<4>(A, pw + PW_DS, w * 4, lane, acc);
  acc_to_c<4>(acc, C, b_ds, w * 4, lane, CS);
  __syncthreads();
  ln_c_to_a<false>(C, A, g_ds, be_ds, w, lane);
  __syncthreads();
  gemm_tile<4>(A, pw + PW_VAL, w * 4, lane, acc);
  acc_to_c<4>(acc, C, b_val, w * 4, lane, CS);
  __syncthreads();
#pragma unroll
  for (int tt = 0; tt < 4; ++tt) {
    const int t = w * 4 + tt, tok = tok0 + t;
    if (tok < NTOK) {
      const float4 v = *reinterpret_cast<const float4*>(&C[t * CS + lane * 4]);
      ushort4 b; b.x = f2b(v.x); b.y = f2b(v.y); b.z = f2b(v.z); b.w = f2b(v.w);
      *reinterpret_cast<ushort4*>(dout + (size_t)tok * 1024 + 512 + lane * 8) = b;
    }
  }
}

// ------------- kernel 2: head GEMMs + softmax + descriptor compute ----------

__global__ __launch_bounds__(256) void k_head(
    const float* __restrict__ tgt, const float* __restrict__ qp,
    const float* __restrict__ ref, const ushort* __restrict__ pw,
    const float* __restrict__ b_off, const float* __restrict__ b_attn,
    unsigned* __restrict__ xy_g, ushort* __restrict__ aw_g) {
  __shared__ __align__(16) ushort A[TT * AS];
  __shared__ __align__(16) float  C[TT * CS];
  __shared__ __align__(16) float  AW[TT * AWS];
  const int tid = threadIdx.x, w = tid >> 6, lane = tid & 63;
  const int tok0 = blockIdx.x * TT;

  load_to_A<true>(tgt, qp, tok0, A, w, lane);
  __syncthreads();

  f32x4 acc[4];
  gemm_tile<4>(A, pw + PW_OFF, w * 4, lane, acc);
  acc_to_c<4>(acc, C, b_off, w * 4, lane, CS);
  {
    f32x4 a2[2];
    gemm_tile<2>(A, pw + PW_ATT, w * 2, lane, a2);
    acc_to_c<2>(a2, AW, b_attn, w * 2, lane, AWS);
  }
  __syncthreads();

  // softmax over 16 per (token, head)
  if (tid < TT * 8) {
    const int t = tid >> 3, h = tid & 7;
    float* a = &AW[t * AWS + h * 16];
    float m = a[0];
#pragma unroll
    for (int i = 1; i < 16; ++i) m = fmaxf(m, a[i]);
    float s = 0.f, e[16];
#pragma unroll
    for (int i = 0; i < 16; ++i) { e[i] = expf(a[i] - m); s += e[i]; }
    const float inv = 1.0f / s;
#pragma unroll
    for (int i = 0; i < 16; ++i) a[i] = e[i] * inv;
  }
  __syncthreads();

  // descriptor compute: thread (tl = tid>>4, c = tid&15 -> (l,p)); i loops heads
  {
    const int tl = tid >> 4, c = tid & 15;
    const int l = c >> 2;
    const int Wl = (l == 0) ? 92 : (l == 1) ? 46 : (l == 2) ? 23 : 12;
    const float fW = (float)Wl;
    const int tok = tok0 + tl;
    const int tokc = (tok < NTOK) ? tok : (NTOK - 1);
    const float refx = ref[(size_t)tokc * 8 + l * 2 + 0];
    const float refy = ref[(size_t)tokc * 8 + l * 2 + 1];
    const float vmask = (tok < NTOK) ? 1.f : 0.f;
#pragma unroll
    for (int i = 0; i < 8; ++i) {
      const int pt = i * 16 + c;   // h*16 + l*4 + p
      const float ox = C[tl * CS + pt * 2 + 0];
      const float oy = C[tl * CS + pt * 2 + 1];
      const float aw = AW[tl * AWS + pt] * vmask;
      float x = fmaf(refx, fW, ox) - 0.5f;
      float y = fmaf(refy, fW, oy) - 0.5f;
      x = fminf(fmaxf(x, -1.f), 126.9f);
      y = fminf(fmaxf(y, -1.f), 126.9f);
      const unsigned ux = (unsigned)(int)rintf((x + 1.f) * 512.f);
      const unsigned uy = (unsigned)(int)rintf((y + 1.f) * 512.f);
      xy_g[(size_t)tok * 128 + pt] = ux | (uy << 16);
      const __half ah = __float2half_rn(aw);
      aw_g[(size_t)tok * 128 + pt] = __half_as_ushort(ah);
    }
  }
}

// ------------- kernel 3: gather (high occupancy, no barriers in hot loop) ---

__global__ __launch_bounds__(256, 6) void k_gather(
    const unsigned* __restrict__ xy_g, const ushort* __restrict__ aw_g,
    unsigned char* __restrict__ dout) {
  __shared__ unsigned sxy[4 * 128];
  __shared__ ushort   saw[4 * 128];
  const int tid = threadIdx.x;
  const int tb0 = blockIdx.x * 4;

  // stage descriptors for 4 tokens (coalesced)
  sxy[tid]       = xy_g[(size_t)tb0 * 128 + tid];
  sxy[tid + 256] = xy_g[(size_t)tb0 * 128 + tid + 256];
  saw[tid]       = aw_g[(size_t)tb0 * 128 + tid];
  saw[tid + 256] = aw_g[(size_t)tb0 * 128 + tid + 256];
  __syncthreads();

  // wave = one token: tl = tid>>6; lanes: h = (tid>>3)&7, sl = tid&7
  const int tl = tid >> 6, h = (tid >> 3) & 7, sl = tid & 7;
  const int tok = tb0 + tl;
  const int bb = (tok >= LQ) ? LQ : 0;
  const int col8 = h * 16 + sl * 2;          // uint index within 128-uint row
  const unsigned char* __restrict__ vb = dout;  // value at slot +512

  float o0 = 0.f, o1 = 0.f, o2 = 0.f, o3 = 0.f;
#pragma unroll
  for (int l = 0; l < 4; ++l) {
    const int Wl  = (l == 0) ? 92 : (l == 1) ? 46 : (l == 2) ? 23 : 12;
    const int lsi = (l == 0) ? 0  : (l == 1) ? 8464 : (l == 2) ? 10580 : 11109;
    const int rbas = bb + lsi;
#pragma unroll
    for (int p = 0; p < 4; ++p) {
      const int pt = l * 4 + p;
      const unsigned uxy = sxy[tl * 128 + h * 16 + pt];
      const float aw = __half2float(__ushort_as_half(saw[tl * 128 + h * 16 + pt]));
      const float x = (float)(uxy & 0xffffu) * (1.f / 512.f) - 1.f;
      const float y = (float)(uxy >> 16)     * (1.f / 512.f) - 1.f;
      const float x0f = floorf(x), y0f = floorf(y);
      const int x0 = (int)x0f, y0 = (int)y0f;
      const float fx = x - x0f, fy = y - y0f;
      const float gx = 1.f - fx, gy = 1.f - fy;
      const float wx0 = ((x0 >= 0) & (x0 < Wl)) ? gx : 0.f;
      const float wx1 = (x0 < Wl - 1) ? fx : 0.f;       // x0+1 >= 0 always (x >= -1)
      const float wy0 = (((y0 >= 0) & (y0 < Wl)) ? gy : 0.f) * aw;
      const float wy1 = ((y0 < Wl - 1) ? fy : 0.f) * aw;
      const float w00 = wx0 * wy0, w10 = wx1 * wy0;
      const float w01 = wx0 * wy1, w11 = wx1 * wy1;
      const int base = rbas + y0 * Wl + x0;
      const int r00 = clampr(base),      r10 = clampr(base + 1);
      const int r01 = clampr(base + Wl), r11 = clampr(base + Wl + 1);
      const uint2 u00 = *(const uint2*)(vb + (size_t)r00 * 1024 + 512 + col8 * 4);
      const uint2 u10 = *(const uint2*)(vb + (size_t)r10 * 1024 + 512 + col8 * 4);
      const uint2 u01 = *(const uint2*)(vb + (size_t)r01 * 1024 + 512 + col8 * 4);
      const uint2 u11 = *(const uint2*)(vb + (size_t)r11 * 1024 + 512 + col8 * 4);
      o0 = fmaf(w00, blo(u00.x), o0); o1 = fmaf(w00, bhi(u00.x), o1);
      o2 = fmaf(w00, blo(u00.y), o2); o3 = fmaf(w00, bhi(u00.y), o3);
      o0 = fmaf(w10, blo(u10.x), o0); o1 = fmaf(w10, bhi(u10.x), o1);
      o2 = fmaf(w10, blo(u10.y), o2); o3 = fmaf(w10, bhi(u10.y), o3);
      o0 = fmaf(w01, blo(u01.x), o0); o1 = fmaf(w01, bhi(u01.x), o1);
      o2 = fmaf(w01, blo(u01.y), o2); o3 = fmaf(w01, bhi(u01.y), o3);
      o0 = fmaf(w11, blo(u11.x), o0); o1 = fmaf(w11, bhi(u11.x), o1);
      o2 = fmaf(w11, blo(u11.y), o2); o3 = fmaf(w11, bhi(u11.y), o3);
    }
  }
  if (tok < NTOK) {
    const unsigned lo = (unsigned)f2b(o0) | ((unsigned)f2b(o1) << 16);
    const unsigned hi = (unsigned)f2b(o2) | ((unsigned)f2b(o3) << 16);
    uint2 st; st.x = lo; st.y = hi;
    *(uint2*)(dout + (size_t)tok * 1024 + col8 * 4) = st;
  }
}

// ------------- kernel 4: tail GEMM chain + LNs + GELU -----------------------

__global__ __launch_bounds__(256) void k_tail(
    const float* __restrict__ tgt, const ushort* __restrict__ pw,
    const float* __restrict__ b_out, const float* __restrict__ b_cs,
    const float* __restrict__ g1, const float* __restrict__ be1,
    const float* __restrict__ b1,
    const float* __restrict__ g2, const float* __restrict__ be2,
    unsigned char* __restrict__ dout) {
  __shared__ __align__(16) ushort A[TT * AS];
  __shared__ __align__(16) float  C[TT * CS];
  const int tid = threadIdx.x, w = tid >> 6, lane = tid & 63;
  const int tok0 = blockIdx.x * TT;

  // load ATT (bf16) rows from our own d_out slots
#pragma unroll
  for (int tt = 0; tt < 4; ++tt) {
    const int t = w * 4 + tt, tok = tok0 + t;
    ushort4 b = make_ushort4(0, 0, 0, 0);
    if (tok < NTOK)
      b = *reinterpret_cast<const ushort4*>(dout + (size_t)tok * 1024 + lane * 8);
    *reinterpret_cast<ushort4*>(&A[t * AS + lane * 4]) = b;
  }
  __syncthreads();

  f32x4 acc[4];
  // t2a = attn @ w_out + b_out
  gemm_tile<4>(A, pw + PW_OUT, w * 4, lane, acc);
  acc_to_c<4>(acc, C, b_out, w * 4, lane, CS);
  __syncthreads();
  c_to_a(C, A, w, lane);
  __syncthreads();

  // t2 = t2a @ w_cs + b_cs + tgt; LN1 -> A bf16 (+ C fp32 kept)
  gemm_tile<4>(A, pw + PW_CS, w * 4, lane, acc);
  {
    const int col = lane & 15, rb = (lane >> 4) * 4;
#pragma unroll
    for (int nt = 0; nt < 4; ++nt) {
      const int dim = (w * 4 + nt) * 16 + col;
      const float bj = b_cs[dim];
#pragma unroll
      for (int i = 0; i < 4; ++i) {
        const int tok = tok0 + rb + i;
        const float tv = (tok < NTOK) ? tgt[(size_t)tok * DM + dim] : 0.f;
        C[(rb + i) * CS + dim] = acc[nt][i] + bj + tv;
      }
    }
  }
  __syncthreads();
  ln_c_to_a<true>(C, A, g1, be1, w, lane);
  __syncthreads();

  // u = gelu(t @ w1 + b1); y = t + u (in-place on C)
  gemm_tile<4>(A, pw + PW_W1, w * 4, lane, acc);
  {
    const int col = lane & 15, rb = (lane >> 4) * 4;
#pragma unroll
    for (int nt = 0; nt < 4; ++nt) {
      const int dim = (w * 4 + nt) * 16 + col;
      const float bj = b1[dim];
#pragma unroll
      for (int i = 0; i < 4; ++i) {
        const float x = acc[nt][i] + bj;
        const float gel = 0.5f * x * (1.0f + erff(x * 0.70710678118654752f));
        const int ci = (rb + i) * CS + dim;
        C[ci] = C[ci] + gel;
      }
    }
  }
  __syncthreads();

  // LN2 -> out (fp32 full slot overwrite)
  float* outp = (float*)dout;
#pragma unroll
  for (int tt = 0; tt < 4; ++tt) {
    const int t = w * 4 + tt, tok = tok0 + t;
    float4 v = *reinterpret_cast<float4*>(&C[t * CS + lane * 4]);
    float s = v.x + v.y + v.z + v.w;
#pragma unroll
    for (int o = 32; o; o >>= 1) s += __shfl_xor(s, o);
    const float m = s * (1.f / 256.f);
    const float d0 = v.x - m, d1 = v.y - m, d2 = v.z - m, d3 = v.w - m;
    float s2 = d0 * d0 + d1 * d1 + d2 * d2 + d3 * d3;
#pragma unroll
    for (int o = 32; o; o >>= 1) s2 += __shfl_xor(s2, o);
    const float rs = rsqrtf(s2 * (1.f / 256.f) + 1e-5f);
    if (tok < NTOK) {
      const float4 gg = *reinterpret_cast<const float4*>(&g2[lane * 4]);
      const float4 bb = *reinterpret_cast<const float4*>(&be2[lane * 4]);
      float4 o4;
      o4.x = d0 * rs * gg.x + bb.x; o4.y = d1 * rs * gg.y + bb.y;
      o4.z = d2 * rs * gg.z + bb.z; o4.w = d3 * rs * gg.w + bb.w;
      *reinterpret_cast<float4*>(&outp[(size_t)tok * DM + lane * 4]) = o4;
    }
  }
}

// ---------------- launch ----------------

extern "C" void kernel_launch(void* const* d_in, const int* in_sizes, int n_in,
                              void* d_out, int out_size, void* d_ws, size_t ws_size,
                              hipStream_t stream) {
  const float* tgt    = (const float*)d_in[0];
  const float* qp     = (const float*)d_in[1];
  const float* ref    = (const float*)d_in[2];
  const float* src    = (const float*)d_in[3];
  const float* w_ds   = (const float*)d_in[6];
  const float* b_ds   = (const float*)d_in[7];
  const float* g_ds   = (const float*)d_in[8];
  const float* be_ds  = (const float*)d_in[9];
  const float* w_off  = (const float*)d_in[10];
  const float* b_off  = (const float*)d_in[11];
  const float* w_attn = (const float*)d_in[12];
  const float* b_attn = (const float*)d_in[13];
  const float* w_val  = (const float*)d_in[14];
  const float* b_val  = (const float*)d_in[15];
  const float* w_out  = (const float*)d_in[16];
  const float* b_out  = (const float*)d_in[17];
  const float* w_cs   = (const float*)d_in[18];
  const float* b_cs   = (const float*)d_in[19];
  const float* g1     = (const float*)d_in[20];
  const float* be1    = (const float*)d_in[21];
  const float* w1     = (const float*)d_in[22];
  const float* b1     = (const float*)d_in[23];
  const float* g2     = (const float*)d_in[24];
  const float* be2    = (const float*)d_in[25];

  ushort*   pw   = (ushort*)d_ws;
  unsigned* xy_g = (unsigned*)((char*)d_ws + XY_WS_OFF);  // NTOKP*128*4 = 11.5 MB
  ushort*   aw_g = (ushort*)((char*)d_ws + AW_WS_OFF);    // NTOKP*128*2 = 5.8 MB
  unsigned char* dout = (unsigned char*)d_out;

  const int nblk = (NTOK + TT - 1) / TT;       // 1407
  const int gblk = (NTOK + 3) / 4;             // 5627
  hipLaunchKernelGGL(k_pack, dim3(208), dim3(256), 0, stream,
                     w_ds, w_val, w_off, w_out, w_cs, w1, w_attn, pw);
  hipLaunchKernelGGL(k_value, dim3(nblk), dim3(256), 0, stream,
                     src, pw, b_ds, g_ds, be_ds, b_val, dout);
  hipLaunchKernelGGL(k_head, dim3(nblk), dim3(256), 0, stream,
                     tgt, qp, ref, pw, b_off, b_attn, xy_g, aw_g);
  hipLaunchKernelGGL(k_gather, dim3(gblk), dim3(256), 0, stream,
                     xy_g, aw_g, dout);
  hipLaunchKernelGGL(k_tail, dim3(nblk), dim3(256), 0, stream,
                     tgt, pw, b_out, b_cs, g1, be1, b1, g2, be2, dout);
}